// Round 3
// baseline (347.056 us; speedup 1.0000x reference)
//
#include <hip/hip_runtime.h>

// Problem constants
#define NHID 256
#define NV   21
#define NT   60
#define NC   4
#define NDCT 60
#define THIS 30
#define NBS  256

__device__ __forceinline__ float ftanh(float x) {
    // tanh(x) = 1 - 2/(exp(2x)+1); exact at +-inf, ~1e-6 rel error
    float e = __expf(2.0f * x);
    return 1.0f - __fdividef(2.0f, e + 1.0f);
}

// ---------------------------------------------------------------------------
// Kernel 1: root-history DCT (pad last frame 29 for t=30..89)
// rhd[n, d*3+k] = sum_{t<30} dct_m[d,t]*x[t,n,ri[k]] + (sum_{t=30..89} dct_m[d,t])*x[29,n,ri[k]]
// x: [30,256,63], dct_m: [60,90]
// ---------------------------------------------------------------------------
__global__ void k_dct(const float* __restrict__ x, const float* __restrict__ dct_m,
                      const int* __restrict__ root_idx, float* __restrict__ rhd)
{
    int gid = blockIdx.x * 256 + threadIdx.x;
    if (gid >= NBS * 180) return;
    int n = gid / 180;
    int r = gid - n * 180;
    int d = r / 3;
    int k = r - d * 3;
    int ri = root_idx[k];
    const float* xp = x + n * 63 + ri;     // + t*16128
    const float* dm = dct_m + d * 90;
    float acc = 0.f;
    #pragma unroll
    for (int t = 0; t < 30; ++t)
        acc += dm[t] * xp[t * 16128];
    float wl = 0.f;
    #pragma unroll
    for (int t = 30; t < 90; ++t)
        wl += dm[t];
    acc += wl * xp[29 * 16128];
    rhd[gid] = acc;
}

// ---------------------------------------------------------------------------
// Kernel 2: fused STSGCN + conv/BN/PReLU + time-encoder + node-encoder.
// One block per batch row n. 512 threads.
// ---------------------------------------------------------------------------
__global__ __launch_bounds__(512, 2) void k_main(
    const float* __restrict__ cont,
    const float* __restrict__ T_c, const float* __restrict__ A_c,
    const float* __restrict__ conv_w, const float* __restrict__ conv_b,
    const float* __restrict__ bn1_scale, const float* __restrict__ bn1_shift,
    const float* __restrict__ resconv_w, const float* __restrict__ resconv_b,
    const float* __restrict__ bnr_scale, const float* __restrict__ bnr_shift,
    const float* __restrict__ prelu_a_p,
    const float* __restrict__ te1_w, const float* __restrict__ te1_b,
    const float* __restrict__ te2_w, const float* __restrict__ te2_b,
    const float* __restrict__ ne1_w, const float* __restrict__ ne1_b,
    const float* __restrict__ ne2_w, const float* __restrict__ ne2_b,
    float* __restrict__ hcont)
{
    __shared__ float xc_lds[5040];   // [t][v][c]
    __shared__ float g_lds[5040];    // [c][q][v]
    __shared__ float g2_lds[5040];   // [t][w][c]
    __shared__ float tew_lds[600];   // [t][j]  (te1_w transposed: te1_w is [10][60])

    const int n = blockIdx.x;
    const int tid = threadIdx.x;

    // stage A: cont[n] -> LDS (layout already [t][v][c]); te1_w transposed -> LDS
    {
        const float4* src = (const float4*)(cont + n * 5040);
        float4* dst = (float4*)xc_lds;
        for (int i = tid; i < 1260; i += 512) dst[i] = src[i];
        // te1_w[j][t] (row-major [10][60]) -> tew_lds[t*10+j]
        // NOTE: 600 > 512 threads -> MUST be a strided loop (bug in prior round)
        for (int i = tid; i < 600; i += 512) {
            int t = i / 10, j = i - t * 10;
            tew_lds[i] = te1_w[j * 60 + t];
        }
    }
    __syncthreads();

    // stage B: temporal adjacency  g[c][q][v] = sum_t xc[t][v][c] * T_c[v][t][q]
    for (int idx = tid; idx < 5040; idx += 512) {
        int c = idx / 1260;
        int r = idx - c * 1260;
        int v = r / 60;
        int q = r - v * 60;
        const float* tc = T_c + v * 3600 + q;   // + t*60
        float acc = 0.f;
        #pragma unroll 4
        for (int t = 0; t < 60; ++t)
            acc += xc_lds[t * 84 + v * 4 + c] * tc[t * 60];
        g_lds[c * 1260 + q * 21 + v] = acc;
    }
    __syncthreads();

    // stage C: spatial adjacency  g2[t][w][c] = sum_v g[c][t][v] * A_c[t][v][w]
    for (int idx = tid; idx < 5040; idx += 512) {
        int c = idx / 1260;
        int r = idx - c * 1260;
        int t = r / 21;
        int w = r - t * 21;
        const float* ac = A_c + t * 441 + w;    // + v*21
        const float* gl = g_lds + c * 1260 + t * 21;
        float acc = 0.f;
        #pragma unroll
        for (int v = 0; v < 21; ++v)
            acc += gl[v] * ac[v * 21];
        g2_lds[t * 84 + w * 4 + c] = acc;
    }
    __syncthreads();

    // main fused loop
    const int og = tid >> 3;     // 0..63  -> o = og*4+g
    const int part = tid & 7;    // 0..7   -> v slice
    const int vstart = (part < 5) ? part * 3 : 15 + (part - 5) * 2;
    const int vcount = (part < 5) ? 3 : 2;

    const float pa = prelu_a_p[0];

    float cA[4][4], cB[4][4], cC[4];
    #pragma unroll
    for (int g = 0; g < 4; ++g) {
        int o = og * 4 + g;
        float s1 = bn1_scale[o], sr = bnr_scale[o];
        #pragma unroll
        for (int c = 0; c < 4; ++c) {
            cA[g][c] = conv_w[o * 4 + c] * s1;
            cB[g][c] = resconv_w[o * 4 + c] * sr;
        }
        cC[g] = conv_b[o] * s1 + bn1_shift[o] + resconv_b[o] * sr + bnr_shift[o];
    }

    float tw2[10], tb1[10];
    #pragma unroll
    for (int j = 0; j < 10; ++j) { tw2[j] = te2_w[j]; tb1[j] = te1_b[j]; }
    const float tb2 = te2_b[0];

    float wacc[4][10];
    #pragma unroll
    for (int g = 0; g < 4; ++g)
        #pragma unroll
        for (int j = 0; j < 10; ++j) wacc[g][j] = 0.f;

    for (int vi = 0; vi < vcount; ++vi) {
        int v = vstart + vi;
        float u[4][10];
        #pragma unroll
        for (int g = 0; g < 4; ++g)
            #pragma unroll
            for (int j = 0; j < 10; ++j) u[g][j] = tb1[j];

        for (int t = 0; t < 60; ++t) {
            float4 xcv = *(const float4*)(xc_lds + t * 84 + v * 4);
            float4 g2v = *(const float4*)(g2_lds + t * 84 + v * 4);
            float tw[10];
            #pragma unroll
            for (int j = 0; j < 10; ++j) tw[j] = tew_lds[t * 10 + j];  // wave-uniform broadcast
            #pragma unroll
            for (int g = 0; g < 4; ++g) {
                float h = cC[g]
                    + cA[g][0] * g2v.x + cA[g][1] * g2v.y + cA[g][2] * g2v.z + cA[g][3] * g2v.w
                    + cB[g][0] * xcv.x + cB[g][1] * xcv.y + cB[g][2] * xcv.z + cB[g][3] * xcv.w;
                h = fmaxf(h, 0.f) + pa * fminf(h, 0.f);   // PReLU
                #pragma unroll
                for (int j = 0; j < 10; ++j) u[g][j] += h * tw[j];
            }
        }

        #pragma unroll
        for (int g = 0; g < 4; ++g) {
            float s = tb2;
            #pragma unroll
            for (int j = 0; j < 10; ++j) s += ftanh(u[g][j]) * tw2[j];
            s = ftanh(s);
            #pragma unroll
            for (int j = 0; j < 10; ++j) wacc[g][j] += s * ne1_w[j * 21 + v];
        }
    }

    // butterfly reduce over the 8 v-parts (tid low 3 bits)
    #pragma unroll
    for (int d = 1; d < 8; d <<= 1)
        #pragma unroll
        for (int g = 0; g < 4; ++g)
            #pragma unroll
            for (int j = 0; j < 10; ++j)
                wacc[g][j] += __shfl_xor(wacc[g][j], d, 64);

    if (part == 0) {
        float nw2[10];
        #pragma unroll
        for (int j = 0; j < 10; ++j) nw2[j] = ne2_w[j];
        float nb2 = ne2_b[0];
        #pragma unroll
        for (int g = 0; g < 4; ++g) {
            int o = og * 4 + g;
            float s = nb2;
            #pragma unroll
            for (int j = 0; j < 10; ++j)
                s += ftanh(wacc[g][j] + ne1_b[j]) * nw2[j];
            hcont[n * 256 + o] = ftanh(s);
        }
    }
}

// ---------------------------------------------------------------------------
// Kernel 3: residual MLP head + IDCT. One block per 4 batch rows, 512 threads.
// thread (o = tid>>1, h = tid&1) splits each dot product in half, shfl_xor(1).
// ---------------------------------------------------------------------------
__global__ __launch_bounds__(512) void k_head(
    const float* __restrict__ rhd, const float* __restrict__ hcont,
    const float* __restrict__ g1_w, const float* __restrict__ g1_b,
    const float* __restrict__ g2a_w, const float* __restrict__ g2a_b,
    const float* __restrict__ g2b_w, const float* __restrict__ g2b_b,
    const float* __restrict__ g3a_w, const float* __restrict__ g3a_b,
    const float* __restrict__ g3b_w, const float* __restrict__ g3b_b,
    const float* __restrict__ g4_w, const float* __restrict__ g4_b,
    const float* __restrict__ idct_m, float* __restrict__ out)
{
    __shared__ float in_lds[4][436];
    __shared__ float rh_lds[4][256];
    __shared__ float tmp_lds[4][256];
    __shared__ float rp_lds[4][180];

    const int tid = threadIdx.x;
    const int n0 = blockIdx.x * 4;
    const int o = tid >> 1;
    const int h = tid & 1;

    for (int i = tid; i < 4 * 436; i += 512) {
        int bn = i / 436, j = i - bn * 436;
        in_lds[bn][j] = (j < 180) ? rhd[(n0 + bn) * 180 + j]
                                  : hcont[(n0 + bn) * 256 + (j - 180)];
    }
    __syncthreads();

    // g1: 436 -> 256, tanh
    {
        const float* wrow = g1_w + o * 436 + h * 218;
        float acc[4] = {0.f, 0.f, 0.f, 0.f};
        for (int i = 0; i < 218; ++i) {
            float wv = wrow[i];
            #pragma unroll
            for (int bn = 0; bn < 4; ++bn) acc[bn] += wv * in_lds[bn][h * 218 + i];
        }
        #pragma unroll
        for (int bn = 0; bn < 4; ++bn) {
            float s = acc[bn] + __shfl_xor(acc[bn], 1, 64);
            if (h == 0) rh_lds[bn][o] = ftanh(s + g1_b[o]);
        }
    }
    __syncthreads();

#define LAYER_PAIR(Wa, ba, Wb, bb)                                             \
    {                                                                          \
        const float* wa = Wa + o * 256 + h * 128;                              \
        float acc[4] = {0.f, 0.f, 0.f, 0.f};                                   \
        for (int i = 0; i < 128; ++i) {                                        \
            float wv = wa[i];                                                  \
            _Pragma("unroll")                                                  \
            for (int bn = 0; bn < 4; ++bn) acc[bn] += wv * rh_lds[bn][h * 128 + i]; \
        }                                                                      \
        _Pragma("unroll")                                                      \
        for (int bn = 0; bn < 4; ++bn) {                                       \
            float s = acc[bn] + __shfl_xor(acc[bn], 1, 64);                    \
            if (h == 0) tmp_lds[bn][o] = ftanh(s + ba[o]);                     \
        }                                                                      \
        __syncthreads();                                                       \
        const float* wb = Wb + o * 256 + h * 128;                              \
        float acc2[4] = {0.f, 0.f, 0.f, 0.f};                                  \
        for (int i = 0; i < 128; ++i) {                                        \
            float wv = wb[i];                                                  \
            _Pragma("unroll")                                                  \
            for (int bn = 0; bn < 4; ++bn) acc2[bn] += wv * tmp_lds[bn][h * 128 + i]; \
        }                                                                      \
        _Pragma("unroll")                                                      \
        for (int bn = 0; bn < 4; ++bn) {                                       \
            float s = acc2[bn] + __shfl_xor(acc2[bn], 1, 64);                  \
            if (h == 0) rh_lds[bn][o] = ftanh(s + bb[o]) + rh_lds[bn][o];      \
        }                                                                      \
        __syncthreads();                                                       \
    }

    LAYER_PAIR(g2a_w, g2a_b, g2b_w, g2b_b)
    LAYER_PAIR(g3a_w, g3a_b, g3b_w, g3b_b)

    // g4: 256 -> 180, + root_his_dct residual
    if (o < 180) {
        const float* wr = g4_w + o * 256 + h * 128;
        float acc[4] = {0.f, 0.f, 0.f, 0.f};
        for (int i = 0; i < 128; ++i) {
            float wv = wr[i];
            #pragma unroll
            for (int bn = 0; bn < 4; ++bn) acc[bn] += wv * rh_lds[bn][h * 128 + i];
        }
        #pragma unroll
        for (int bn = 0; bn < 4; ++bn) {
            float s = acc[bn] + __shfl_xor(acc[bn], 1, 64);
            if (h == 0) rp_lds[bn][o] = s + g4_b[o] + in_lds[bn][o];
        }
    }
    __syncthreads();

    // IDCT: out[n,t,k] = sum_d idct_m[t,d] * rp[n][d*3+k]
    for (int idx = tid; idx < 4 * 270; idx += 512) {
        int bn = idx / 270;
        int r = idx - bn * 270;
        int t = r / 3;
        int k = r - t * 3;
        const float* im = idct_m + t * 60;
        const float* rp = &rp_lds[bn][k];
        float acc = 0.f;
        #pragma unroll
        for (int d = 0; d < 60; ++d)
            acc += im[d] * rp[d * 3];
        out[(n0 + bn) * 270 + r] = acc;
    }
}

// ---------------------------------------------------------------------------
extern "C" void kernel_launch(void* const* d_in, const int* in_sizes, int n_in,
                              void* d_out, int out_size, void* d_ws, size_t ws_size,
                              hipStream_t stream)
{
    const float* x        = (const float*)d_in[0];
    const float* cont     = (const float*)d_in[1];
    // d_in[2] cont_mask unused
    const float* dct_m    = (const float*)d_in[3];
    const float* idct_m   = (const float*)d_in[4];
    const int*   root_idx = (const int*)d_in[5];
    // d_in[6] horizon unused (hardcoded 60)
    const float* T_c      = (const float*)d_in[7];
    const float* A_c      = (const float*)d_in[8];
    const float* conv_w   = (const float*)d_in[9];
    const float* conv_b   = (const float*)d_in[10];
    const float* bn1_s    = (const float*)d_in[11];
    const float* bn1_sh   = (const float*)d_in[12];
    const float* rconv_w  = (const float*)d_in[13];
    const float* rconv_b  = (const float*)d_in[14];
    const float* bnr_s    = (const float*)d_in[15];
    const float* bnr_sh   = (const float*)d_in[16];
    const float* prelu_a  = (const float*)d_in[17];
    const float* te1_w    = (const float*)d_in[18];
    const float* te1_b    = (const float*)d_in[19];
    const float* te2_w    = (const float*)d_in[20];
    const float* te2_b    = (const float*)d_in[21];
    const float* ne1_w    = (const float*)d_in[22];
    const float* ne1_b    = (const float*)d_in[23];
    const float* ne2_w    = (const float*)d_in[24];
    const float* ne2_b    = (const float*)d_in[25];
    const float* g1_w     = (const float*)d_in[26];
    const float* g1_b     = (const float*)d_in[27];
    const float* g2a_w    = (const float*)d_in[28];
    const float* g2a_b    = (const float*)d_in[29];
    const float* g2b_w    = (const float*)d_in[30];
    const float* g2b_b    = (const float*)d_in[31];
    const float* g3a_w    = (const float*)d_in[32];
    const float* g3a_b    = (const float*)d_in[33];
    const float* g3b_w    = (const float*)d_in[34];
    const float* g3b_b    = (const float*)d_in[35];
    const float* g4_w     = (const float*)d_in[36];
    const float* g4_b     = (const float*)d_in[37];

    float* rhd   = (float*)d_ws;           // 256*180 = 46080 floats
    float* hcont = rhd + 46080;            // 256*256 = 65536 floats

    k_dct<<<(NBS * 180 + 255) / 256, 256, 0, stream>>>(x, dct_m, root_idx, rhd);

    k_main<<<NBS, 512, 0, stream>>>(cont, T_c, A_c,
                                    conv_w, conv_b, bn1_s, bn1_sh,
                                    rconv_w, rconv_b, bnr_s, bnr_sh,
                                    prelu_a,
                                    te1_w, te1_b, te2_w, te2_b,
                                    ne1_w, ne1_b, ne2_w, ne2_b,
                                    hcont);

    k_head<<<NBS / 4, 512, 0, stream>>>(rhd, hcont,
                                        g1_w, g1_b, g2a_w, g2a_b, g2b_w, g2b_b,
                                        g3a_w, g3a_b, g3b_w, g3b_b, g4_w, g4_b,
                                        idct_m, (float*)d_out);
}

// Round 4
// 301.540 us; speedup vs baseline: 1.1509x; 1.1509x over previous
//
#include <hip/hip_runtime.h>

// Problem constants
#define NHID 256
#define NV   21
#define NT   60
#define NC   4
#define NDCT 60
#define THIS 30
#define NBS  256

__device__ __forceinline__ float ftanh(float x) {
    // tanh(x) = 1 - 2/(exp(2x)+1); exact at +-inf, ~1e-6 rel error
    float e = __expf(2.0f * x);
    return 1.0f - __fdividef(2.0f, e + 1.0f);
}

// ---------------------------------------------------------------------------
// Kernel 1: root-history DCT (pad last frame 29 for t=30..89)
// rhd[n, d*3+k] = sum_{t<30} dct_m[d,t]*x[t,n,ri[k]] + (sum_{t=30..89} dct_m[d,t])*x[29,n,ri[k]]
// x: [30,256,63], dct_m: [60,90]
// ---------------------------------------------------------------------------
__global__ void k_dct(const float* __restrict__ x, const float* __restrict__ dct_m,
                      const int* __restrict__ root_idx, float* __restrict__ rhd)
{
    int gid = blockIdx.x * 256 + threadIdx.x;
    if (gid >= NBS * 180) return;
    int n = gid / 180;
    int r = gid - n * 180;
    int d = r / 3;
    int k = r - d * 3;
    int ri = root_idx[k];
    const float* xp = x + n * 63 + ri;     // + t*16128
    const float* dm = dct_m + d * 90;
    float acc = 0.f;
    #pragma unroll
    for (int t = 0; t < 30; ++t)
        acc += dm[t] * xp[t * 16128];
    float wl = 0.f;
    #pragma unroll
    for (int t = 30; t < 90; ++t)
        wl += dm[t];
    acc += wl * xp[29 * 16128];
    rhd[gid] = acc;
}

// ---------------------------------------------------------------------------
// Kernel 2: fused STSGCN + conv/BN/PReLU + time-encoder + node-encoder.
// TWO blocks per batch row n (grid 512): block half handles 128 o-channels.
// 512 threads, G=2 o-channels per thread, 8 v-parts.
// ---------------------------------------------------------------------------
__global__ __launch_bounds__(512, 4) void k_main(
    const float* __restrict__ cont,
    const float* __restrict__ T_c, const float* __restrict__ A_c,
    const float* __restrict__ conv_w, const float* __restrict__ conv_b,
    const float* __restrict__ bn1_scale, const float* __restrict__ bn1_shift,
    const float* __restrict__ resconv_w, const float* __restrict__ resconv_b,
    const float* __restrict__ bnr_scale, const float* __restrict__ bnr_shift,
    const float* __restrict__ prelu_a_p,
    const float* __restrict__ te1_w, const float* __restrict__ te1_b,
    const float* __restrict__ te2_w, const float* __restrict__ te2_b,
    const float* __restrict__ ne1_w, const float* __restrict__ ne1_b,
    const float* __restrict__ ne2_w, const float* __restrict__ ne2_b,
    float* __restrict__ hcont)
{
    __shared__ __align__(16) float xc_lds[5040];   // [t][v][c]
    __shared__ __align__(16) float g_lds[5040];    // [c][q][v]
    __shared__ __align__(16) float g2_lds[5040];   // [t][w][c]
    __shared__ __align__(16) float tew_lds[720];   // [t][12] padded (te1_w is [10][60])

    const int n    = blockIdx.x >> 1;
    const int half = blockIdx.x & 1;
    const int tid  = threadIdx.x;

    // stage A: cont[n] -> LDS (layout already [t][v][c]); te1_w transposed+padded -> LDS
    {
        const float4* src = (const float4*)(cont + n * 5040);
        float4* dst = (float4*)xc_lds;
        for (int i = tid; i < 1260; i += 512) dst[i] = src[i];
        for (int i = tid; i < 720; i += 512) {
            int t = i / 12, j = i - t * 12;
            tew_lds[i] = (j < 10) ? te1_w[j * 60 + t] : 0.f;
        }
    }
    __syncthreads();

    // stage B: temporal adjacency  g[c][q][v] = sum_t xc[t][v][c] * T_c[v][t][q]
    for (int idx = tid; idx < 5040; idx += 512) {
        int c = idx / 1260;
        int r = idx - c * 1260;
        int v = r / 60;
        int q = r - v * 60;
        const float* tc = T_c + v * 3600 + q;   // + t*60
        float acc = 0.f;
        #pragma unroll 4
        for (int t = 0; t < 60; ++t)
            acc += xc_lds[t * 84 + v * 4 + c] * tc[t * 60];
        g_lds[c * 1260 + q * 21 + v] = acc;
    }
    __syncthreads();

    // stage C: spatial adjacency  g2[t][w][c] = sum_v g[c][t][v] * A_c[t][v][w]
    for (int idx = tid; idx < 5040; idx += 512) {
        int c = idx / 1260;
        int r = idx - c * 1260;
        int t = r / 21;
        int w = r - t * 21;
        const float* ac = A_c + t * 441 + w;    // + v*21
        const float* gl = g_lds + c * 1260 + t * 21;
        float acc = 0.f;
        #pragma unroll
        for (int v = 0; v < 21; ++v)
            acc += gl[v] * ac[v * 21];
        g2_lds[t * 84 + w * 4 + c] = acc;
    }
    __syncthreads();

    // main fused loop: this block covers o in [half*128, half*128+128)
    const int og = tid >> 3;     // 0..63  -> o = half*128 + og*2 + g
    const int part = tid & 7;    // 0..7   -> v slice
    const int vstart = (part < 5) ? part * 3 : 15 + (part - 5) * 2;
    const int vcount = (part < 5) ? 3 : 2;
    const int obase = half * 128 + og * 2;

    const float pa = prelu_a_p[0];

    float cA[2][4], cB[2][4], cC[2];
    #pragma unroll
    for (int g = 0; g < 2; ++g) {
        int o = obase + g;
        float s1 = bn1_scale[o], sr = bnr_scale[o];
        #pragma unroll
        for (int c = 0; c < 4; ++c) {
            cA[g][c] = conv_w[o * 4 + c] * s1;
            cB[g][c] = resconv_w[o * 4 + c] * sr;
        }
        cC[g] = conv_b[o] * s1 + bn1_shift[o] + resconv_b[o] * sr + bnr_shift[o];
    }

    float tw2[10], tb1[10];
    #pragma unroll
    for (int j = 0; j < 10; ++j) { tw2[j] = te2_w[j]; tb1[j] = te1_b[j]; }
    const float tb2 = te2_b[0];

    float wacc[2][10];
    #pragma unroll
    for (int g = 0; g < 2; ++g)
        #pragma unroll
        for (int j = 0; j < 10; ++j) wacc[g][j] = 0.f;

    for (int vi = 0; vi < vcount; ++vi) {
        int v = vstart + vi;
        float u[2][10];
        #pragma unroll
        for (int g = 0; g < 2; ++g)
            #pragma unroll
            for (int j = 0; j < 10; ++j) u[g][j] = tb1[j];

        for (int t = 0; t < 60; ++t) {
            float4 xcv = *(const float4*)(xc_lds + t * 84 + v * 4);
            float4 g2v = *(const float4*)(g2_lds + t * 84 + v * 4);
            float4 twA = *(const float4*)(tew_lds + t * 12);
            float4 twB = *(const float4*)(tew_lds + t * 12 + 4);
            float2 twC = *(const float2*)(tew_lds + t * 12 + 8);
            #pragma unroll
            for (int g = 0; g < 2; ++g) {
                float h = cC[g]
                    + cA[g][0] * g2v.x + cA[g][1] * g2v.y + cA[g][2] * g2v.z + cA[g][3] * g2v.w
                    + cB[g][0] * xcv.x + cB[g][1] * xcv.y + cB[g][2] * xcv.z + cB[g][3] * xcv.w;
                h = fmaxf(h, 0.f) + pa * fminf(h, 0.f);   // PReLU
                u[g][0] += h * twA.x; u[g][1] += h * twA.y;
                u[g][2] += h * twA.z; u[g][3] += h * twA.w;
                u[g][4] += h * twB.x; u[g][5] += h * twB.y;
                u[g][6] += h * twB.z; u[g][7] += h * twB.w;
                u[g][8] += h * twC.x; u[g][9] += h * twC.y;
            }
        }

        float nw[10];
        #pragma unroll
        for (int j = 0; j < 10; ++j) nw[j] = ne1_w[j * 21 + v];
        #pragma unroll
        for (int g = 0; g < 2; ++g) {
            float s = tb2;
            #pragma unroll
            for (int j = 0; j < 10; ++j) s += ftanh(u[g][j]) * tw2[j];
            s = ftanh(s);
            #pragma unroll
            for (int j = 0; j < 10; ++j) wacc[g][j] += s * nw[j];
        }
    }

    // butterfly reduce over the 8 v-parts (tid low 3 bits)
    #pragma unroll
    for (int d = 1; d < 8; d <<= 1)
        #pragma unroll
        for (int g = 0; g < 2; ++g)
            #pragma unroll
            for (int j = 0; j < 10; ++j)
                wacc[g][j] += __shfl_xor(wacc[g][j], d, 64);

    if (part == 0) {
        float nw2[10];
        #pragma unroll
        for (int j = 0; j < 10; ++j) nw2[j] = ne2_w[j];
        float nb2 = ne2_b[0];
        #pragma unroll
        for (int g = 0; g < 2; ++g) {
            int o = obase + g;
            float s = nb2;
            #pragma unroll
            for (int j = 0; j < 10; ++j)
                s += ftanh(wacc[g][j] + ne1_b[j]) * nw2[j];
            hcont[n * 256 + o] = ftanh(s);
        }
    }
}

// ---------------------------------------------------------------------------
// Kernel 3: residual MLP head + IDCT. One block per 4 batch rows, 512 threads.
// 16 lanes cooperate per output row (coalesced float4 weight loads),
// 32 groups x 8 outputs each = 256 outputs. Butterfly-reduce over 16 lanes.
// ---------------------------------------------------------------------------
__global__ __launch_bounds__(512) void k_head(
    const float* __restrict__ rhd, const float* __restrict__ hcont,
    const float* __restrict__ g1_w, const float* __restrict__ g1_b,
    const float* __restrict__ g2a_w, const float* __restrict__ g2a_b,
    const float* __restrict__ g2b_w, const float* __restrict__ g2b_b,
    const float* __restrict__ g3a_w, const float* __restrict__ g3a_b,
    const float* __restrict__ g3b_w, const float* __restrict__ g3b_b,
    const float* __restrict__ g4_w, const float* __restrict__ g4_b,
    const float* __restrict__ idct_m, float* __restrict__ out)
{
    __shared__ __align__(16) float in_lds[4 * 436];   // concat(rhd, hcont)
    __shared__ __align__(16) float a_lds[4 * 256];    // rh
    __shared__ __align__(16) float b_lds[4 * 256];    // tmp
    __shared__ __align__(16) float rp_lds[4 * 180];

    const int tid = threadIdx.x;
    const int n0 = blockIdx.x * 4;
    const int gid = tid >> 4;     // 0..31 (8 outputs each)
    const int sub = tid & 15;     // 0..15 (k-slice lanes)

    for (int i = tid; i < 4 * 436; i += 512) {
        int bn = i / 436, j = i - bn * 436;
        in_lds[i] = (j < 180) ? rhd[(n0 + bn) * 180 + j]
                              : hcont[(n0 + bn) * 256 + (j - 180)];
    }
    __syncthreads();

// Dense layer: K inputs, 256 outputs. SRC: LDS base (row stride SSTR).
// BODY(oo, o, bn, sumv) consumes the reduced sum.
#define DENSE_CORE(KDIM, NSWEEP, W, SRC, SSTR, GUARD_O, BODY)                   \
    {                                                                           \
        float acc[8][4] = {};                                                   \
        for (int s = 0; s < NSWEEP; ++s) {                                      \
            int k4 = s * 16 + sub;                                              \
            if (k4 * 4 < KDIM) {                                                \
                float4 av0 = *(const float4*)&SRC[0 * SSTR + k4 * 4];           \
                float4 av1 = *(const float4*)&SRC[1 * SSTR + k4 * 4];           \
                float4 av2 = *(const float4*)&SRC[2 * SSTR + k4 * 4];           \
                float4 av3 = *(const float4*)&SRC[3 * SSTR + k4 * 4];           \
                _Pragma("unroll")                                               \
                for (int oo = 0; oo < 8; ++oo) {                                \
                    int o = gid * 8 + oo;                                       \
                    if (GUARD_O) {                                              \
                        float4 wv = *(const float4*)&W[o * KDIM + k4 * 4];      \
                        acc[oo][0] += wv.x*av0.x + wv.y*av0.y + wv.z*av0.z + wv.w*av0.w; \
                        acc[oo][1] += wv.x*av1.x + wv.y*av1.y + wv.z*av1.z + wv.w*av1.w; \
                        acc[oo][2] += wv.x*av2.x + wv.y*av2.y + wv.z*av2.z + wv.w*av2.w; \
                        acc[oo][3] += wv.x*av3.x + wv.y*av3.y + wv.z*av3.z + wv.w*av3.w; \
                    }                                                           \
                }                                                               \
            }                                                                   \
        }                                                                       \
        _Pragma("unroll")                                                       \
        for (int m = 1; m < 16; m <<= 1) {                                      \
            _Pragma("unroll")                                                   \
            for (int oo = 0; oo < 8; ++oo) {                                    \
                _Pragma("unroll")                                               \
                for (int bn = 0; bn < 4; ++bn)                                  \
                    acc[oo][bn] += __shfl_xor(acc[oo][bn], m, 64);              \
            }                                                                   \
        }                                                                       \
        _Pragma("unroll")                                                       \
        for (int oo = 0; oo < 8; ++oo) {                                        \
            int o = gid * 8 + oo;                                               \
            if (GUARD_O) {                                                      \
                _Pragma("unroll")                                               \
                for (int bn = 0; bn < 4; ++bn) { float sumv = acc[oo][bn]; BODY } \
            }                                                                   \
        }                                                                       \
    }                                                                           \
    __syncthreads();

    // g1: 436 -> 256, tanh -> a_lds
    DENSE_CORE(436, 7, g1_w, in_lds, 436, true,
        { float val = ftanh(sumv + g1_b[o]);
          if (sub == 0) a_lds[bn * 256 + o] = val; })

    // g2a: a -> b, tanh
    DENSE_CORE(256, 4, g2a_w, a_lds, 256, true,
        { float val = ftanh(sumv + g2a_b[o]);
          if (sub == 0) b_lds[bn * 256 + o] = val; })

    // g2b: b -> a, tanh + residual(a)
    DENSE_CORE(256, 4, g2b_w, b_lds, 256, true,
        { float val = ftanh(sumv + g2b_b[o]) + a_lds[bn * 256 + o];
          if (sub == 0) a_lds[bn * 256 + o] = val; })

    // g3a: a -> b, tanh
    DENSE_CORE(256, 4, g3a_w, a_lds, 256, true,
        { float val = ftanh(sumv + g3a_b[o]);
          if (sub == 0) b_lds[bn * 256 + o] = val; })

    // g3b: b -> a, tanh + residual(a)
    DENSE_CORE(256, 4, g3b_w, b_lds, 256, true,
        { float val = ftanh(sumv + g3b_b[o]) + a_lds[bn * 256 + o];
          if (sub == 0) a_lds[bn * 256 + o] = val; })

    // g4: a -> rp (180 outputs), no tanh, + root_his_dct residual
    DENSE_CORE(256, 4, g4_w, a_lds, 256, (o < 180),
        { float val = sumv + g4_b[o] + in_lds[bn * 436 + o];
          if (sub == 0) rp_lds[bn * 180 + o] = val; })

    // IDCT: out[n,t,k] = sum_d idct_m[t,d] * rp[n][d*3+k]
    for (int idx = tid; idx < 4 * 270; idx += 512) {
        int bn = idx / 270;
        int r = idx - bn * 270;
        int t = r / 3;
        int k = r - t * 3;
        const float* im = idct_m + t * 60;
        const float* rp = rp_lds + bn * 180 + k;
        float acc = 0.f;
        #pragma unroll
        for (int d = 0; d < 60; ++d)
            acc += im[d] * rp[d * 3];
        out[(n0 + bn) * 270 + r] = acc;
    }
}

// ---------------------------------------------------------------------------
extern "C" void kernel_launch(void* const* d_in, const int* in_sizes, int n_in,
                              void* d_out, int out_size, void* d_ws, size_t ws_size,
                              hipStream_t stream)
{
    const float* x        = (const float*)d_in[0];
    const float* cont     = (const float*)d_in[1];
    // d_in[2] cont_mask unused
    const float* dct_m    = (const float*)d_in[3];
    const float* idct_m   = (const float*)d_in[4];
    const int*   root_idx = (const int*)d_in[5];
    // d_in[6] horizon unused (hardcoded 60)
    const float* T_c      = (const float*)d_in[7];
    const float* A_c      = (const float*)d_in[8];
    const float* conv_w   = (const float*)d_in[9];
    const float* conv_b   = (const float*)d_in[10];
    const float* bn1_s    = (const float*)d_in[11];
    const float* bn1_sh   = (const float*)d_in[12];
    const float* rconv_w  = (const float*)d_in[13];
    const float* rconv_b  = (const float*)d_in[14];
    const float* bnr_s    = (const float*)d_in[15];
    const float* bnr_sh   = (const float*)d_in[16];
    const float* prelu_a  = (const float*)d_in[17];
    const float* te1_w    = (const float*)d_in[18];
    const float* te1_b    = (const float*)d_in[19];
    const float* te2_w    = (const float*)d_in[20];
    const float* te2_b    = (const float*)d_in[21];
    const float* ne1_w    = (const float*)d_in[22];
    const float* ne1_b    = (const float*)d_in[23];
    const float* ne2_w    = (const float*)d_in[24];
    const float* ne2_b    = (const float*)d_in[25];
    const float* g1_w     = (const float*)d_in[26];
    const float* g1_b     = (const float*)d_in[27];
    const float* g2a_w    = (const float*)d_in[28];
    const float* g2a_b    = (const float*)d_in[29];
    const float* g2b_w    = (const float*)d_in[30];
    const float* g2b_b    = (const float*)d_in[31];
    const float* g3a_w    = (const float*)d_in[32];
    const float* g3a_b    = (const float*)d_in[33];
    const float* g3b_w    = (const float*)d_in[34];
    const float* g3b_b    = (const float*)d_in[35];
    const float* g4_w     = (const float*)d_in[36];
    const float* g4_b     = (const float*)d_in[37];

    float* rhd   = (float*)d_ws;           // 256*180 = 46080 floats
    float* hcont = rhd + 46080;            // 256*256 = 65536 floats

    k_dct<<<(NBS * 180 + 255) / 256, 256, 0, stream>>>(x, dct_m, root_idx, rhd);

    k_main<<<NBS * 2, 512, 0, stream>>>(cont, T_c, A_c,
                                        conv_w, conv_b, bn1_s, bn1_sh,
                                        rconv_w, rconv_b, bnr_s, bnr_sh,
                                        prelu_a,
                                        te1_w, te1_b, te2_w, te2_b,
                                        ne1_w, ne1_b, ne2_w, ne2_b,
                                        hcont);

    k_head<<<NBS / 4, 512, 0, stream>>>(rhd, hcont,
                                        g1_w, g1_b, g2a_w, g2a_b, g2b_w, g2b_b,
                                        g3a_w, g3a_b, g3b_w, g3b_b, g4_w, g4_b,
                                        idct_m, (float*)d_out);
}

// Round 5
// 270.671 us; speedup vs baseline: 1.2822x; 1.1140x over previous
//
#include <hip/hip_runtime.h>

// Problem constants
#define NHID 256
#define NV   21
#define NT   60
#define NC   4
#define NDCT 60
#define THIS 30
#define NBS  256

__device__ __forceinline__ float ftanh(float x) {
    // tanh(x) = 1 - 2/(exp(2x)+1); exact at +-inf, ~1e-6 rel error
    float e = __expf(2.0f * x);
    return 1.0f - __fdividef(2.0f, e + 1.0f);
}

// ---------------------------------------------------------------------------
// Kernel 1: fused STSGCN + conv/BN/PReLU + time-encoder + node-encoder.
// ONE block per batch row n. 512 threads (8 waves).
//   A: xc_lds[t][v][c] = cont[n]
//   B: g_lds[q][v][c]  = sum_t xc[t][v][c] * T_c[v][t][q]   (c-vectorized, q-pairs)
//   C: g2_lds[t][w][c] = sum_v g[t][v][c] * A_c[t][v][w]    (c-vectorized, w-pairs)
//   main: thread (og=tid>>3, part=tid&7): 4 o-channels, v-slice;
//         tw[j] from te1_w via uniform (scalar) loads — NOT LDS.
// ---------------------------------------------------------------------------
__global__ __launch_bounds__(512, 2) void k_main(
    const float* __restrict__ cont,
    const float* __restrict__ T_c, const float* __restrict__ A_c,
    const float* __restrict__ conv_w, const float* __restrict__ conv_b,
    const float* __restrict__ bn1_scale, const float* __restrict__ bn1_shift,
    const float* __restrict__ resconv_w, const float* __restrict__ resconv_b,
    const float* __restrict__ bnr_scale, const float* __restrict__ bnr_shift,
    const float* __restrict__ prelu_a_p,
    const float* __restrict__ te1_w, const float* __restrict__ te1_b,
    const float* __restrict__ te2_w, const float* __restrict__ te2_b,
    const float* __restrict__ ne1_w, const float* __restrict__ ne1_b,
    const float* __restrict__ ne2_w, const float* __restrict__ ne2_b,
    float* __restrict__ hcont)
{
    __shared__ __align__(16) float xc_lds[5040];   // [t][v][c]
    __shared__ __align__(16) float g_lds[5040];    // [q][v][c]
    __shared__ __align__(16) float g2_lds[5040];   // [t][w][c]

    const int n   = blockIdx.x;
    const int tid = threadIdx.x;

    // ---- stage A: cont[n] -> LDS (layout already [t][v][c]) ----
    {
        const float4* src = (const float4*)(cont + n * 5040);
        float4* dst = (float4*)xc_lds;
        for (int i = tid; i < 1260; i += 512) dst[i] = src[i];
    }
    __syncthreads();

    // ---- stage B: g[q][v][c] = sum_t xc[t][v][c] * T_c[v][t][q], q-pairs ----
    for (int task = tid; task < 630; task += 512) {
        int v  = task / 30;          // 0..20
        int q0 = (task - v * 30) * 2; // 0,2,..,58
        const float* tc = T_c + v * 3600 + q0;   // + t*60
        float4 a0 = {0.f,0.f,0.f,0.f}, a1 = {0.f,0.f,0.f,0.f};
        #pragma unroll 4
        for (int t = 0; t < 60; ++t) {
            float4 xcv = *(const float4*)(xc_lds + t * 84 + v * 4);
            float2 tq  = *(const float2*)(tc + t * 60);   // 8B-aligned (q0 even)
            a0.x += xcv.x * tq.x; a0.y += xcv.y * tq.x;
            a0.z += xcv.z * tq.x; a0.w += xcv.w * tq.x;
            a1.x += xcv.x * tq.y; a1.y += xcv.y * tq.y;
            a1.z += xcv.z * tq.y; a1.w += xcv.w * tq.y;
        }
        *(float4*)(g_lds + q0 * 84 + v * 4)       = a0;
        *(float4*)(g_lds + (q0 + 1) * 84 + v * 4) = a1;
    }
    __syncthreads();

    // ---- stage C: g2[t][w][c] = sum_v g[t][v][c] * A_c[t][v][w], w-pairs ----
    for (int task = tid; task < 660; task += 512) {
        int t  = task / 11;            // 0..59
        int w0 = (task - t * 11) * 2;  // 0,2,..,20 (w0==20 -> single)
        const bool has2 = (w0 < 20);
        const float* ac = A_c + t * 441 + w0;   // + v*21
        float4 a0 = {0.f,0.f,0.f,0.f}, a1 = {0.f,0.f,0.f,0.f};
        #pragma unroll
        for (int v = 0; v < 21; ++v) {
            float4 gv = *(const float4*)(g_lds + t * 84 + v * 4);
            float b0 = ac[v * 21];
            float b1 = has2 ? ac[v * 21 + 1] : 0.f;
            a0.x += gv.x * b0; a0.y += gv.y * b0;
            a0.z += gv.z * b0; a0.w += gv.w * b0;
            a1.x += gv.x * b1; a1.y += gv.y * b1;
            a1.z += gv.z * b1; a1.w += gv.w * b1;
        }
        *(float4*)(g2_lds + t * 84 + w0 * 4) = a0;
        if (has2) *(float4*)(g2_lds + t * 84 + (w0 + 1) * 4) = a1;
    }
    __syncthreads();

    // ---- main fused loop ----
    const int og = tid >> 3;     // 0..63  -> o = og*4+g
    const int part = tid & 7;    // 0..7   -> v slice
    const int vstart = (part < 5) ? part * 3 : 15 + (part - 5) * 2;
    const int vcount = (part < 5) ? 3 : 2;

    const float pa = prelu_a_p[0];

    float cA[4][4], cB[4][4], cC[4];
    #pragma unroll
    for (int g = 0; g < 4; ++g) {
        int o = og * 4 + g;
        float s1 = bn1_scale[o], sr = bnr_scale[o];
        #pragma unroll
        for (int c = 0; c < 4; ++c) {
            cA[g][c] = conv_w[o * 4 + c] * s1;
            cB[g][c] = resconv_w[o * 4 + c] * sr;
        }
        cC[g] = conv_b[o] * s1 + bn1_shift[o] + resconv_b[o] * sr + bnr_shift[o];
    }

    float tw2[10], tb1[10];
    #pragma unroll
    for (int j = 0; j < 10; ++j) { tw2[j] = te2_w[j]; tb1[j] = te1_b[j]; }
    const float tb2 = te2_b[0];

    float wacc[4][10];
    #pragma unroll
    for (int g = 0; g < 4; ++g)
        #pragma unroll
        for (int j = 0; j < 10; ++j) wacc[g][j] = 0.f;

    for (int vi = 0; vi < vcount; ++vi) {
        int v = vstart + vi;
        float u[4][10];
        #pragma unroll
        for (int g = 0; g < 4; ++g)
            #pragma unroll
            for (int j = 0; j < 10; ++j) u[g][j] = tb1[j];

        for (int t = 0; t < 60; ++t) {
            float4 xcv = *(const float4*)(xc_lds + t * 84 + v * 4);
            float4 g2v = *(const float4*)(g2_lds + t * 84 + v * 4);
            // tw: uniform index (loop counter) -> scalar loads, off LDS/VMEM pipes
            float tw[10];
            #pragma unroll
            for (int j = 0; j < 10; ++j) tw[j] = te1_w[j * 60 + t];
            #pragma unroll
            for (int g = 0; g < 4; ++g) {
                float h = cC[g]
                    + cA[g][0] * g2v.x + cA[g][1] * g2v.y + cA[g][2] * g2v.z + cA[g][3] * g2v.w
                    + cB[g][0] * xcv.x + cB[g][1] * xcv.y + cB[g][2] * xcv.z + cB[g][3] * xcv.w;
                h = fmaxf(h, 0.f) + pa * fminf(h, 0.f);   // PReLU
                #pragma unroll
                for (int j = 0; j < 10; ++j) u[g][j] += h * tw[j];
            }
        }

        float nw[10];
        #pragma unroll
        for (int j = 0; j < 10; ++j) nw[j] = ne1_w[j * 21 + v];
        #pragma unroll
        for (int g = 0; g < 4; ++g) {
            float s = tb2;
            #pragma unroll
            for (int j = 0; j < 10; ++j) s += ftanh(u[g][j]) * tw2[j];
            s = ftanh(s);
            #pragma unroll
            for (int j = 0; j < 10; ++j) wacc[g][j] += s * nw[j];
        }
    }

    // butterfly reduce over the 8 v-parts (tid low 3 bits)
    #pragma unroll
    for (int d = 1; d < 8; d <<= 1)
        #pragma unroll
        for (int g = 0; g < 4; ++g)
            #pragma unroll
            for (int j = 0; j < 10; ++j)
                wacc[g][j] += __shfl_xor(wacc[g][j], d, 64);

    if (part == 0) {
        float nw2[10];
        #pragma unroll
        for (int j = 0; j < 10; ++j) nw2[j] = ne2_w[j];
        float nb2 = ne2_b[0];
        #pragma unroll
        for (int g = 0; g < 4; ++g) {
            int o = og * 4 + g;
            float s = nb2;
            #pragma unroll
            for (int j = 0; j < 10; ++j)
                s += ftanh(wacc[g][j] + ne1_b[j]) * nw2[j];
            hcont[n * 256 + o] = ftanh(s);
        }
    }
}

// ---------------------------------------------------------------------------
// Kernel 2: root-DCT + residual MLP head + IDCT. One block per 2 batch rows,
// 512 threads. k-split over 8 lanes (3 shfl rounds), 64 groups x 4 outputs.
// ---------------------------------------------------------------------------
__global__ __launch_bounds__(512) void k_head(
    const float* __restrict__ x, const float* __restrict__ dct_m,
    const int* __restrict__ root_idx, const float* __restrict__ hcont,
    const float* __restrict__ g1_w, const float* __restrict__ g1_b,
    const float* __restrict__ g2a_w, const float* __restrict__ g2a_b,
    const float* __restrict__ g2b_w, const float* __restrict__ g2b_b,
    const float* __restrict__ g3a_w, const float* __restrict__ g3a_b,
    const float* __restrict__ g3b_w, const float* __restrict__ g3b_b,
    const float* __restrict__ g4_w, const float* __restrict__ g4_b,
    const float* __restrict__ idct_m, float* __restrict__ out)
{
    __shared__ __align__(16) float in_lds[2 * 436];   // concat(rhd, hcont)
    __shared__ __align__(16) float a_lds[2 * 256];
    __shared__ __align__(16) float b_lds[2 * 256];
    __shared__ __align__(16) float rp_lds[2 * 180];

    const int tid = threadIdx.x;
    const int n0 = blockIdx.x * 2;
    const int gid = tid >> 3;     // 0..63 (4 outputs each)
    const int sub = tid & 7;      // 0..7  (k-slice lanes)

    // stage hcont into in_lds[.][180..435]
    {
        int bn = tid >> 8, j = tid & 255;
        in_lds[bn * 436 + 180 + j] = hcont[(n0 + bn) * 256 + j];
    }
    // root-history DCT directly into in_lds[.][0..179]
    for (int i = tid; i < 360; i += 512) {
        int bn = i / 180, r = i - bn * 180;
        int d = r / 3, k = r - d * 3;
        int ri = root_idx[k];
        const float* xp = x + (n0 + bn) * 63 + ri;   // + t*16128
        const float* dm = dct_m + d * 90;
        float acc = 0.f;
        #pragma unroll
        for (int t = 0; t < 30; ++t)
            acc += dm[t] * xp[t * 16128];
        float wl = 0.f;
        #pragma unroll
        for (int t = 30; t < 90; ++t)
            wl += dm[t];
        acc += wl * xp[29 * 16128];
        in_lds[bn * 436 + r] = acc;
    }
    __syncthreads();

// Dense layer: K inputs, 256 outputs, 2 batch rows. 8-lane k-split.
#define DENSE_CORE(KDIM, NSWEEP, W, SRC, SSTR, GUARD_O, BODY)                   \
    {                                                                           \
        float acc[4][2] = {};                                                   \
        for (int s = 0; s < NSWEEP; ++s) {                                      \
            int k4 = s * 8 + sub;                                               \
            if (k4 * 4 < KDIM) {                                                \
                float4 av0 = *(const float4*)&SRC[0 * SSTR + k4 * 4];           \
                float4 av1 = *(const float4*)&SRC[1 * SSTR + k4 * 4];           \
                _Pragma("unroll")                                               \
                for (int oo = 0; oo < 4; ++oo) {                                \
                    int o = gid * 4 + oo;                                       \
                    if (GUARD_O) {                                              \
                        float4 wv = *(const float4*)&W[o * KDIM + k4 * 4];      \
                        acc[oo][0] += wv.x*av0.x + wv.y*av0.y + wv.z*av0.z + wv.w*av0.w; \
                        acc[oo][1] += wv.x*av1.x + wv.y*av1.y + wv.z*av1.z + wv.w*av1.w; \
                    }                                                           \
                }                                                               \
            }                                                                   \
        }                                                                       \
        _Pragma("unroll")                                                       \
        for (int m = 1; m < 8; m <<= 1) {                                       \
            _Pragma("unroll")                                                   \
            for (int oo = 0; oo < 4; ++oo) {                                    \
                acc[oo][0] += __shfl_xor(acc[oo][0], m, 64);                    \
                acc[oo][1] += __shfl_xor(acc[oo][1], m, 64);                    \
            }                                                                   \
        }                                                                       \
        if (sub == 0) {                                                         \
            _Pragma("unroll")                                                   \
            for (int oo = 0; oo < 4; ++oo) {                                    \
                int o = gid * 4 + oo;                                           \
                if (GUARD_O) {                                                  \
                    _Pragma("unroll")                                           \
                    for (int bn = 0; bn < 2; ++bn) { float sumv = acc[oo][bn]; BODY } \
                }                                                               \
            }                                                                   \
        }                                                                       \
    }                                                                           \
    __syncthreads();

    // g1: 436 -> 256, tanh -> a
    DENSE_CORE(436, 14, g1_w, in_lds, 436, true,
        { a_lds[bn * 256 + o] = ftanh(sumv + g1_b[o]); })

    // g2a: a -> b, tanh
    DENSE_CORE(256, 8, g2a_w, a_lds, 256, true,
        { b_lds[bn * 256 + o] = ftanh(sumv + g2a_b[o]); })

    // g2b: b -> a, tanh + residual(a)
    DENSE_CORE(256, 8, g2b_w, b_lds, 256, true,
        { a_lds[bn * 256 + o] = ftanh(sumv + g2b_b[o]) + a_lds[bn * 256 + o]; })

    // g3a: a -> b, tanh
    DENSE_CORE(256, 8, g3a_w, a_lds, 256, true,
        { b_lds[bn * 256 + o] = ftanh(sumv + g3a_b[o]); })

    // g3b: b -> a, tanh + residual(a)
    DENSE_CORE(256, 8, g3b_w, b_lds, 256, true,
        { a_lds[bn * 256 + o] = ftanh(sumv + g3b_b[o]) + a_lds[bn * 256 + o]; })

    // g4: a -> rp (180 outputs), + root_his_dct residual
    DENSE_CORE(256, 8, g4_w, a_lds, 256, (o < 180),
        { rp_lds[bn * 180 + o] = sumv + g4_b[o] + in_lds[bn * 436 + o]; })

    // IDCT: out[n,t,k] = sum_d idct_m[t,d] * rp[n][d*3+k]
    for (int idx = tid; idx < 2 * 270; idx += 512) {
        int bn = idx / 270;
        int r = idx - bn * 270;
        int t = r / 3;
        int k = r - t * 3;
        const float* im = idct_m + t * 60;
        const float* rp = rp_lds + bn * 180 + k;
        float acc = 0.f;
        #pragma unroll
        for (int d = 0; d < 60; ++d)
            acc += im[d] * rp[d * 3];
        out[(n0 + bn) * 270 + r] = acc;
    }
}

// ---------------------------------------------------------------------------
extern "C" void kernel_launch(void* const* d_in, const int* in_sizes, int n_in,
                              void* d_out, int out_size, void* d_ws, size_t ws_size,
                              hipStream_t stream)
{
    const float* x        = (const float*)d_in[0];
    const float* cont     = (const float*)d_in[1];
    // d_in[2] cont_mask unused
    const float* dct_m    = (const float*)d_in[3];
    const float* idct_m   = (const float*)d_in[4];
    const int*   root_idx = (const int*)d_in[5];
    // d_in[6] horizon unused (hardcoded 60)
    const float* T_c      = (const float*)d_in[7];
    const float* A_c      = (const float*)d_in[8];
    const float* conv_w   = (const float*)d_in[9];
    const float* conv_b   = (const float*)d_in[10];
    const float* bn1_s    = (const float*)d_in[11];
    const float* bn1_sh   = (const float*)d_in[12];
    const float* rconv_w  = (const float*)d_in[13];
    const float* rconv_b  = (const float*)d_in[14];
    const float* bnr_s    = (const float*)d_in[15];
    const float* bnr_sh   = (const float*)d_in[16];
    const float* prelu_a  = (const float*)d_in[17];
    const float* te1_w    = (const float*)d_in[18];
    const float* te1_b    = (const float*)d_in[19];
    const float* te2_w    = (const float*)d_in[20];
    const float* te2_b    = (const float*)d_in[21];
    const float* ne1_w    = (const float*)d_in[22];
    const float* ne1_b    = (const float*)d_in[23];
    const float* ne2_w    = (const float*)d_in[24];
    const float* ne2_b    = (const float*)d_in[25];
    const float* g1_w     = (const float*)d_in[26];
    const float* g1_b     = (const float*)d_in[27];
    const float* g2a_w    = (const float*)d_in[28];
    const float* g2a_b    = (const float*)d_in[29];
    const float* g2b_w    = (const float*)d_in[30];
    const float* g2b_b    = (const float*)d_in[31];
    const float* g3a_w    = (const float*)d_in[32];
    const float* g3a_b    = (const float*)d_in[33];
    const float* g3b_w    = (const float*)d_in[34];
    const float* g3b_b    = (const float*)d_in[35];
    const float* g4_w     = (const float*)d_in[36];
    const float* g4_b     = (const float*)d_in[37];

    float* hcont = (float*)d_ws;           // 256*256 floats

    k_main<<<NBS, 512, 0, stream>>>(cont, T_c, A_c,
                                    conv_w, conv_b, bn1_s, bn1_sh,
                                    rconv_w, rconv_b, bnr_s, bnr_sh,
                                    prelu_a,
                                    te1_w, te1_b, te2_w, te2_b,
                                    ne1_w, ne1_b, ne2_w, ne2_b,
                                    hcont);

    k_head<<<NBS / 2, 512, 0, stream>>>(x, dct_m, root_idx, hcont,
                                        g1_w, g1_b, g2a_w, g2a_b, g2b_w, g2b_b,
                                        g3a_w, g3a_b, g3b_w, g3b_b, g4_w, g4_b,
                                        idct_m, (float*)d_out);
}

// Round 6
// 250.030 us; speedup vs baseline: 1.3881x; 1.0826x over previous
//
#include <hip/hip_runtime.h>

// Problem constants
#define NHID 256
#define NV   21
#define NT   60
#define NC   4
#define NDCT 60
#define THIS 30
#define NBS  256

__device__ __forceinline__ float ftanh(float x) {
    // tanh(x) = 1 - 2/(exp(2x)+1); exact at +-inf, ~1e-6 rel error
    float e = __expf(2.0f * x);
    return 1.0f - __fdividef(2.0f, e + 1.0f);
}

// ---------------------------------------------------------------------------
// ONE kernel, one block per batch row n, 1024 threads (16 waves/CU).
// Phase 1 (STSGCN + encoders):
//   A: xc_lds[t][v][c] = cont[n]
//   B: g_lds[q][v][c]  = sum_t xc[t][v][c] * T_c[v][t][q]   (q-pairs, c-vec)
//   C: g2_lds[t][w][c] = sum_v g[t][v][c] * A_c[t][v][w]    (w-pairs, c-vec)
//   DCT: root-history DCT -> head_lds[0..179]  (g_lds reused; dead after C)
//   main: thread (og=tid>>3 in 0..127, part=tid&7): 2 o-channels, v-slice;
//         hcont[o] -> head_lds[180+o] (LDS only, never global)
// Phase 2 (residual MLP head + IDCT), all in-block:
//   gid=tid>>2 (=output o), sub=tid&3 (k-split), 2 shfl rounds per layer.
// ---------------------------------------------------------------------------
__global__ __launch_bounds__(1024, 4) void k_all(
    const float* __restrict__ x,
    const float* __restrict__ cont,
    const float* __restrict__ dct_m, const float* __restrict__ idct_m,
    const int* __restrict__ root_idx,
    const float* __restrict__ T_c, const float* __restrict__ A_c,
    const float* __restrict__ conv_w, const float* __restrict__ conv_b,
    const float* __restrict__ bn1_scale, const float* __restrict__ bn1_shift,
    const float* __restrict__ resconv_w, const float* __restrict__ resconv_b,
    const float* __restrict__ bnr_scale, const float* __restrict__ bnr_shift,
    const float* __restrict__ prelu_a_p,
    const float* __restrict__ te1_w, const float* __restrict__ te1_b,
    const float* __restrict__ te2_w, const float* __restrict__ te2_b,
    const float* __restrict__ ne1_w, const float* __restrict__ ne1_b,
    const float* __restrict__ ne2_w, const float* __restrict__ ne2_b,
    const float* __restrict__ g1_w, const float* __restrict__ g1_b,
    const float* __restrict__ g2a_w, const float* __restrict__ g2a_b,
    const float* __restrict__ g2b_w, const float* __restrict__ g2b_b,
    const float* __restrict__ g3a_w, const float* __restrict__ g3a_b,
    const float* __restrict__ g3b_w, const float* __restrict__ g3b_b,
    const float* __restrict__ g4_w, const float* __restrict__ g4_b,
    float* __restrict__ out)
{
    __shared__ __align__(16) float xc_lds[5040];   // [t][v][c]
    __shared__ __align__(16) float g_lds[5040];    // [q][v][c]; reused in phase 2
    __shared__ __align__(16) float g2_lds[5040];   // [t][w][c]

    // phase-2 scratch carved out of g_lds (dead after stage C):
    float* in2 = g_lds;          // [436] = concat(root_dct, hcont)
    float* aL  = g_lds + 436;    // [256]
    float* bL  = g_lds + 692;    // [256]
    float* rp  = g_lds + 948;    // [180]

    const int n   = blockIdx.x;
    const int tid = threadIdx.x;

    // ---- stage A: cont[n] -> LDS (layout already [t][v][c]) ----
    {
        const float4* src = (const float4*)(cont + n * 5040);
        float4* dst = (float4*)xc_lds;
        for (int i = tid; i < 1260; i += 1024) dst[i] = src[i];
    }
    __syncthreads();

    // ---- stage B: g[q][v][c] = sum_t xc[t][v][c] * T_c[v][t][q], q-pairs ----
    for (int task = tid; task < 630; task += 1024) {
        int v  = task / 30;           // 0..20
        int q0 = (task - v * 30) * 2; // 0,2,..,58
        const float* tc = T_c + v * 3600 + q0;   // + t*60
        float4 a0 = {0.f,0.f,0.f,0.f}, a1 = {0.f,0.f,0.f,0.f};
        #pragma unroll 4
        for (int t = 0; t < 60; ++t) {
            float4 xcv = *(const float4*)(xc_lds + t * 84 + v * 4);
            float2 tq  = *(const float2*)(tc + t * 60);   // 8B-aligned (q0 even)
            a0.x += xcv.x * tq.x; a0.y += xcv.y * tq.x;
            a0.z += xcv.z * tq.x; a0.w += xcv.w * tq.x;
            a1.x += xcv.x * tq.y; a1.y += xcv.y * tq.y;
            a1.z += xcv.z * tq.y; a1.w += xcv.w * tq.y;
        }
        *(float4*)(g_lds + q0 * 84 + v * 4)       = a0;
        *(float4*)(g_lds + (q0 + 1) * 84 + v * 4) = a1;
    }
    __syncthreads();

    // ---- stage C: g2[t][w][c] = sum_v g[t][v][c] * A_c[t][v][w], w-pairs ----
    for (int task = tid; task < 660; task += 1024) {
        int t  = task / 11;            // 0..59
        int w0 = (task - t * 11) * 2;  // 0,2,..,20 (w0==20 -> single)
        const bool has2 = (w0 < 20);
        const float* ac = A_c + t * 441 + w0;   // + v*21
        float4 a0 = {0.f,0.f,0.f,0.f}, a1 = {0.f,0.f,0.f,0.f};
        #pragma unroll
        for (int v = 0; v < 21; ++v) {
            float4 gv = *(const float4*)(g_lds + t * 84 + v * 4);
            float b0 = ac[v * 21];
            float b1 = has2 ? ac[v * 21 + 1] : 0.f;
            a0.x += gv.x * b0; a0.y += gv.y * b0;
            a0.z += gv.z * b0; a0.w += gv.w * b0;
            a1.x += gv.x * b1; a1.y += gv.y * b1;
            a1.z += gv.z * b1; a1.w += gv.w * b1;
        }
        *(float4*)(g2_lds + t * 84 + w0 * 4) = a0;
        if (has2) *(float4*)(g2_lds + t * 84 + (w0 + 1) * 4) = a1;
    }
    __syncthreads();
    // g_lds is now dead as adjacency scratch -> becomes head scratch (in2/aL/bL/rp)

    // ---- root-history DCT for this row -> in2[0..179] (overlaps main loop) ----
    if (tid < 180) {
        int d = tid / 3, k = tid - d * 3;
        int ri = root_idx[k];
        const float* xp = x + n * 63 + ri;   // + t*16128
        const float* dm = dct_m + d * 90;
        float acc = 0.f;
        #pragma unroll
        for (int t = 0; t < 30; ++t)
            acc += dm[t] * xp[t * 16128];
        float wl = 0.f;
        #pragma unroll
        for (int t = 30; t < 90; ++t)
            wl += dm[t];
        acc += wl * xp[29 * 16128];
        in2[tid] = acc;
    }

    // ---- main fused loop: 2 o-channels per thread ----
    {
        const int og = tid >> 3;     // 0..127 -> o = og*2+g
        const int part = tid & 7;    // 0..7   -> v slice
        const int vstart = (part < 5) ? part * 3 : 15 + (part - 5) * 2;
        const int vcount = (part < 5) ? 3 : 2;

        const float pa = prelu_a_p[0];

        float cA[2][4], cB[2][4], cC[2];
        #pragma unroll
        for (int g = 0; g < 2; ++g) {
            int o = og * 2 + g;
            float s1 = bn1_scale[o], sr = bnr_scale[o];
            #pragma unroll
            for (int c = 0; c < 4; ++c) {
                cA[g][c] = conv_w[o * 4 + c] * s1;
                cB[g][c] = resconv_w[o * 4 + c] * sr;
            }
            cC[g] = conv_b[o] * s1 + bn1_shift[o] + resconv_b[o] * sr + bnr_shift[o];
        }

        float tw2[10], tb1[10];
        #pragma unroll
        for (int j = 0; j < 10; ++j) { tw2[j] = te2_w[j]; tb1[j] = te1_b[j]; }
        const float tb2 = te2_b[0];

        float wacc[2][10];
        #pragma unroll
        for (int g = 0; g < 2; ++g)
            #pragma unroll
            for (int j = 0; j < 10; ++j) wacc[g][j] = 0.f;

        for (int vi = 0; vi < vcount; ++vi) {
            int v = vstart + vi;
            float u[2][10];
            #pragma unroll
            for (int g = 0; g < 2; ++g)
                #pragma unroll
                for (int j = 0; j < 10; ++j) u[g][j] = tb1[j];

            for (int t = 0; t < 60; ++t) {
                float4 xcv = *(const float4*)(xc_lds + t * 84 + v * 4);
                float4 g2v = *(const float4*)(g2_lds + t * 84 + v * 4);
                // tw: uniform address -> scalar loads (off LDS/VMEM vector pipes)
                float tw[10];
                #pragma unroll
                for (int j = 0; j < 10; ++j) tw[j] = te1_w[j * 60 + t];
                #pragma unroll
                for (int g = 0; g < 2; ++g) {
                    float h = cC[g]
                        + cA[g][0] * g2v.x + cA[g][1] * g2v.y + cA[g][2] * g2v.z + cA[g][3] * g2v.w
                        + cB[g][0] * xcv.x + cB[g][1] * xcv.y + cB[g][2] * xcv.z + cB[g][3] * xcv.w;
                    h = fmaxf(h, 0.f) + pa * fminf(h, 0.f);   // PReLU
                    #pragma unroll
                    for (int j = 0; j < 10; ++j) u[g][j] += h * tw[j];
                }
            }

            float nw[10];
            #pragma unroll
            for (int j = 0; j < 10; ++j) nw[j] = ne1_w[j * 21 + v];
            #pragma unroll
            for (int g = 0; g < 2; ++g) {
                float s = tb2;
                #pragma unroll
                for (int j = 0; j < 10; ++j) s += ftanh(u[g][j]) * tw2[j];
                s = ftanh(s);
                #pragma unroll
                for (int j = 0; j < 10; ++j) wacc[g][j] += s * nw[j];
            }
        }

        // butterfly reduce over the 8 v-parts (tid low 3 bits)
        #pragma unroll
        for (int d = 1; d < 8; d <<= 1)
            #pragma unroll
            for (int g = 0; g < 2; ++g)
                #pragma unroll
                for (int j = 0; j < 10; ++j)
                    wacc[g][j] += __shfl_xor(wacc[g][j], d, 64);

        if (part == 0) {
            float nw2[10];
            #pragma unroll
            for (int j = 0; j < 10; ++j) nw2[j] = ne2_w[j];
            float nb2 = ne2_b[0];
            #pragma unroll
            for (int g = 0; g < 2; ++g) {
                int o = og * 2 + g;
                float s = nb2;
                #pragma unroll
                for (int j = 0; j < 10; ++j)
                    s += ftanh(wacc[g][j] + ne1_b[j]) * nw2[j];
                in2[180 + o] = ftanh(s);     // hcont stays in LDS
            }
        }
    }
    __syncthreads();

    // ---- phase 2: residual MLP head, 4-lane k-split per output ----
    const int gid = tid >> 2;    // 0..255 = output index o
    const int sub = tid & 3;     // 0..3   = k-slice lane

// K inputs (NCHUNK = K/4 float4 chunks), 256 outputs. BODY uses (o, sumv).
#define DENSE(KDIM, NCHUNK, W, SRC, BODY)                                      \
    {                                                                          \
        float acc = 0.f;                                                       \
        _Pragma("unroll")                                                      \
        for (int s = 0; s < (NCHUNK + 3) / 4; ++s) {                           \
            int c4 = s * 4 + sub;                                              \
            if (c4 < NCHUNK) {                                                 \
                float4 av = *(const float4*)&SRC[c4 * 4];                      \
                float4 wv = *(const float4*)&W[gid * KDIM + c4 * 4];           \
                acc += wv.x*av.x + wv.y*av.y + wv.z*av.z + wv.w*av.w;          \
            }                                                                  \
        }                                                                      \
        acc += __shfl_xor(acc, 1, 64);                                         \
        acc += __shfl_xor(acc, 2, 64);                                         \
        if (sub == 0) { int o = gid; float sumv = acc; BODY }                  \
    }                                                                          \
    __syncthreads();

    // g1: 436 -> 256, tanh
    DENSE(436, 109, g1_w, in2, { aL[o] = ftanh(sumv + g1_b[o]); })
    // g2a: 256 -> 256, tanh
    DENSE(256, 64, g2a_w, aL, { bL[o] = ftanh(sumv + g2a_b[o]); })
    // g2b: + residual
    DENSE(256, 64, g2b_w, bL, { aL[o] = ftanh(sumv + g2b_b[o]) + aL[o]; })
    // g3a
    DENSE(256, 64, g3a_w, aL, { bL[o] = ftanh(sumv + g3a_b[o]); })
    // g3b: + residual
    DENSE(256, 64, g3b_w, bL, { aL[o] = ftanh(sumv + g3b_b[o]) + aL[o]; })
    // g4: 256 -> 180, + root_his_dct residual
    DENSE(256, 64, g4_w, aL, { if (o < 180) rp[o] = sumv + g4_b[o] + in2[o]; })

    // ---- IDCT: out[n,t,k] = sum_d idct_m[t,d] * rp[d*3+k] ----
    if (tid < 270) {
        int t = tid / 3;
        int k = tid - t * 3;
        const float* im = idct_m + t * 60;
        const float* rpp = rp + k;
        float acc = 0.f;
        #pragma unroll
        for (int d = 0; d < 60; ++d)
            acc += im[d] * rpp[d * 3];
        out[n * 270 + tid] = acc;
    }
}

// ---------------------------------------------------------------------------
extern "C" void kernel_launch(void* const* d_in, const int* in_sizes, int n_in,
                              void* d_out, int out_size, void* d_ws, size_t ws_size,
                              hipStream_t stream)
{
    const float* x        = (const float*)d_in[0];
    const float* cont     = (const float*)d_in[1];
    // d_in[2] cont_mask unused
    const float* dct_m    = (const float*)d_in[3];
    const float* idct_m   = (const float*)d_in[4];
    const int*   root_idx = (const int*)d_in[5];
    // d_in[6] horizon unused (hardcoded 60)
    const float* T_c      = (const float*)d_in[7];
    const float* A_c      = (const float*)d_in[8];
    const float* conv_w   = (const float*)d_in[9];
    const float* conv_b   = (const float*)d_in[10];
    const float* bn1_s    = (const float*)d_in[11];
    const float* bn1_sh   = (const float*)d_in[12];
    const float* rconv_w  = (const float*)d_in[13];
    const float* rconv_b  = (const float*)d_in[14];
    const float* bnr_s    = (const float*)d_in[15];
    const float* bnr_sh   = (const float*)d_in[16];
    const float* prelu_a  = (const float*)d_in[17];
    const float* te1_w    = (const float*)d_in[18];
    const float* te1_b    = (const float*)d_in[19];
    const float* te2_w    = (const float*)d_in[20];
    const float* te2_b    = (const float*)d_in[21];
    const float* ne1_w    = (const float*)d_in[22];
    const float* ne1_b    = (const float*)d_in[23];
    const float* ne2_w    = (const float*)d_in[24];
    const float* ne2_b    = (const float*)d_in[25];
    const float* g1_w     = (const float*)d_in[26];
    const float* g1_b     = (const float*)d_in[27];
    const float* g2a_w    = (const float*)d_in[28];
    const float* g2a_b    = (const float*)d_in[29];
    const float* g2b_w    = (const float*)d_in[30];
    const float* g2b_b    = (const float*)d_in[31];
    const float* g3a_w    = (const float*)d_in[32];
    const float* g3a_b    = (const float*)d_in[33];
    const float* g3b_w    = (const float*)d_in[34];
    const float* g3b_b    = (const float*)d_in[35];
    const float* g4_w     = (const float*)d_in[36];
    const float* g4_b     = (const float*)d_in[37];

    k_all<<<NBS, 1024, 0, stream>>>(x, cont, dct_m, idct_m, root_idx,
                                    T_c, A_c,
                                    conv_w, conv_b, bn1_s, bn1_sh,
                                    rconv_w, rconv_b, bnr_s, bnr_sh,
                                    prelu_a,
                                    te1_w, te1_b, te2_w, te2_b,
                                    ne1_w, ne1_b, ne2_w, ne2_b,
                                    g1_w, g1_b, g2a_w, g2a_b, g2b_w, g2b_b,
                                    g3a_w, g3a_b, g3b_w, g3b_b, g4_w, g4_b,
                                    (float*)d_out);
}